// Round 12
// baseline (195.932 us; speedup 1.0000x reference)
//
#include <hip/hip_runtime.h>
#include <math.h>
#include <stdint.h>

#define N_NODES 50000
#define N_EDGES 800000
#define IN_DIM  512
#define OUT_DIM 256
#define NBLK_SCAN 49   // ceil(50000/1024)

typedef __attribute__((ext_vector_type(8))) short short8;
typedef __attribute__((ext_vector_type(4))) float f32x4;

__device__ inline unsigned f2bf(float x) {
  unsigned u = __float_as_uint(x);
  return (u + 0x7FFFu + ((u >> 16) & 1u)) >> 16;   // RNE
}
__device__ inline float bf2f(unsigned short h) {
  return __uint_as_float(((unsigned)h) << 16);
}

// ---------------- K1: W [512][256] -> Wtp frag-major bf16 -------------------
// Frag layout: for col-tile nt(0..15), k-step kk(0..15), lane(0..63), j(0..7):
//   Wtp[((nt*16+kk)*64 + lane)*8 + j] = bf16( W[k][c] )
//   with k = kk*32 + (lane>>4)*8 + j, c = nt*16 + (lane&15)
__global__ __launch_bounds__(256) void wconv(const float* __restrict__ W,
                                             unsigned short* __restrict__ Wtp) {
  int i = blockIdx.x * 256 + threadIdx.x;   // over 131072
  int c = i & 255, k = i >> 8;              // coalesced read over c
  int nt = c >> 4, kk = k >> 5;
  int lane = (((k & 31) >> 3) << 4) | (c & 15);
  int j = k & 7;
  Wtp[(((size_t)(nt * 16 + kk)) * 64 + lane) * 8 + j] =
      (unsigned short)f2bf(W[(size_t)k * OUT_DIM + c]);
}

// ---------------- K2: ft = bf16(feat @ W + b), feat-in-LDS, W from L2 -------
// block: 512 thr = 8 waves; tile = 32 rows x 256 cols, full K in one pass.
// LDS = 32 KB -> 4 blocks/CU (32 waves/CU, full wave slots) so staging HBM
// latency of any block hides under other blocks' MFMA. W-frags streamed from
// L2 inside the kk loop (Wtp = 256 KB, L2-resident).
// LDS frag-major: byte = ((mg*16+kk)*64 + slot)*16 + (lane&1)*8,
//   stage: kk = half*8+(lane>>3), slot = (((lane>>1)&3)<<4 | (r&15)) ^ (lane>>3)
//   read:  slot = lane ^ (kk&7)
#define GBM 32
__global__ __launch_bounds__(512) void gemm_mfma(const float* __restrict__ feat,
                        const unsigned short* __restrict__ Wtp,
                        const float* __restrict__ bias,
                        const float* __restrict__ Wl, const float* __restrict__ bl,
                        const float* __restrict__ Wr, const float* __restrict__ br,
                        unsigned short* __restrict__ ftb,
                        float* __restrict__ el, float* __restrict__ er) {
  extern __shared__ char smem[];
  const int tid  = threadIdx.x;
  const int lane = tid & 63;
  const int wv   = tid >> 6;          // 0..7
  const int m0   = blockIdx.x * GBM;

  // Wl/Wr held in 16 regs (loaded once; each lane covers k4 = lane, 64+lane)
  const float4* wl4 = (const float4*)Wl;
  const float4* wr4 = (const float4*)Wr;
  float4 wlA = wl4[lane], wlB = wl4[64 + lane];
  float4 wrA = wr4[lane], wrB = wr4[64 + lane];

  // ---- stage: wave wv stages rows [wv*4, wv*4+4), 1KB-contig per instr ----
  for (int rr = 0; rr < 4; ++rr) {
    int r = wv * 4 + rr;
    int grow = m0 + r;
    int gc = grow < N_NODES ? grow : N_NODES - 1;
    const float4* frow = (const float4*)(feat + (size_t)gc * IN_DIM);
    float elp = 0.f, erp = 0.f;
    #pragma unroll
    for (int half = 0; half < 2; ++half) {
      int k4 = half * 64 + lane;          // float4 index 0..127
      float4 f  = frow[k4];
      float4 wl = half ? wlB : wlA;
      float4 wr = half ? wrB : wrA;
      elp += f.x * wl.x + f.y * wl.y + f.z * wl.z + f.w * wl.w;
      erp += f.x * wr.x + f.y * wr.y + f.z * wr.z + f.w * wr.w;
      uint2 pv;
      pv.x = f2bf(f.x) | (f2bf(f.y) << 16);
      pv.y = f2bf(f.z) | (f2bf(f.w) << 16);
      int kk   = half * 8 + (lane >> 3);
      int slot = ((((lane >> 1) & 3) << 4) | (r & 15)) ^ (lane >> 3);
      int boff = ((((r >> 4) * 16 + kk) * 64) + slot) * 16 + (lane & 1) * 8;
      *(uint2*)(smem + boff) = pv;
    }
    #pragma unroll
    for (int o = 32; o > 0; o >>= 1) {
      elp += __shfl_xor(elp, o);
      erp += __shfl_xor(erp, o);
    }
    if (lane == 0 && grow < N_NODES) {
      el[grow] = elp + bl[0];
      er[grow] = erp + br[0];
    }
  }
  __syncthreads();

  // ---- compute: LDS feat + L2 W-frags + MFMA ----
  f32x4 acc[2][2];
  #pragma unroll
  for (int mg = 0; mg < 2; ++mg) {
    acc[mg][0] = (f32x4)0.f;
    acc[mg][1] = (f32x4)0.f;
  }
  const int nt0 = wv * 2;
  #pragma unroll
  for (int kk = 0; kk < 16; ++kk) {
    short8 w0 = *(const short8*)(Wtp + (((size_t)((nt0 + 0) * 16 + kk)) * 64 + lane) * 8);
    short8 w1 = *(const short8*)(Wtp + (((size_t)((nt0 + 1) * 16 + kk)) * 64 + lane) * 8);
    #pragma unroll
    for (int mg = 0; mg < 2; ++mg) {
      short8 fa = *(const short8*)(smem + (((mg * 16 + kk) * 64) + (lane ^ (kk & 7))) * 16);
      acc[mg][0] = __builtin_amdgcn_mfma_f32_16x16x32_bf16(w0, fa, acc[mg][0], 0, 0, 0);
      acc[mg][1] = __builtin_amdgcn_mfma_f32_16x16x32_bf16(w1, fa, acc[mg][1], 0, 0, 0);
    }
  }

  // ---- store: row = m0+mg*16+(l&15), col = nt*16 + (l>>4)*4 + reg ----
  #pragma unroll
  for (int mg = 0; mg < 2; ++mg) {
    int row = m0 + mg * 16 + (lane & 15);
    if (row < N_NODES) {
      unsigned short* orow = ftb + (size_t)row * OUT_DIM;
      #pragma unroll
      for (int t = 0; t < 2; ++t) {
        int col = (nt0 + t) * 16 + (lane >> 4) * 4;
        float4 bb = *(const float4*)(bias + col);
        f32x4 v = acc[mg][t];
        uint2 pv;
        pv.x = f2bf(v[0] + bb.x) | (f2bf(v[1] + bb.y) << 16);
        pv.y = f2bf(v[2] + bb.z) | (f2bf(v[3] + bb.w) << 16);
        *(uint2*)(orow + col) = pv;
      }
    }
  }
}

// ---------------- K3: degree histogram --------------------------------------
__global__ void deg_count(const int* __restrict__ dst, int* __restrict__ deg) {
  int e = blockIdx.x * blockDim.x + threadIdx.x;
  if (e < N_EDGES) atomicAdd(&deg[dst[e]], 1);
}

// ---------------- K4: parallel exclusive scan (3 stages) --------------------
__global__ __launch_bounds__(1024) void scan_local(const int* __restrict__ deg,
                                                   int* __restrict__ off,
                                                   int* __restrict__ bsum) {
  __shared__ int buf[1024];
  int b = blockIdx.x, t = threadIdx.x, i = b * 1024 + t;
  int v = (i < N_NODES) ? deg[i] : 0;
  buf[t] = v;
  __syncthreads();
  for (int d = 1; d < 1024; d <<= 1) {
    int x = (t >= d) ? buf[t - d] : 0;
    __syncthreads();
    buf[t] += x;
    __syncthreads();
  }
  if (i < N_NODES) off[i] = buf[t] - v;     // exclusive (local)
  if (t == 1023) bsum[b] = buf[t];
}

__global__ void scan_bsums(const int* __restrict__ bsum, int* __restrict__ bscan,
                           int* __restrict__ offN) {
  int t = threadIdx.x;                      // 64 threads, 1 block
  int v = (t < NBLK_SCAN) ? bsum[t] : 0;
  int orig = v;
  for (int d = 1; d < 64; d <<= 1) {
    int x = __shfl_up(v, d);
    if (t >= d) v += x;
  }
  if (t < NBLK_SCAN) bscan[t] = v - orig;   // exclusive
  if (t == NBLK_SCAN - 1) offN[0] = v;      // total == N_EDGES
}

__global__ void add_bscan(int* __restrict__ off, const int* __restrict__ bscan) {
  int i = blockIdx.x * 256 + threadIdx.x;
  if (i < N_NODES) off[i] += bscan[i >> 10];
}

// ---------------- K5: scatter edges into CSR + edge score (int2 packed) -----
__global__ void scatter_edges(const int* __restrict__ src, const int* __restrict__ dst,
                              const float* __restrict__ el, const float* __restrict__ er,
                              const int* __restrict__ off, int* __restrict__ cnt,
                              int2* __restrict__ sed) {
  int e = blockIdx.x * blockDim.x + threadIdx.x;
  if (e >= N_EDGES) return;
  int s = src[e], d = dst[e];
  int pos = off[d] + atomicAdd(&cnt[d], 1);
  float ev = el[s] + er[d];
  ev = (ev > 0.f ? ev : 0.f) + 1.0f;
  int2 pv; pv.x = s; pv.y = __float_as_int(ev);
  sed[pos] = pv;
}

// ---------------- K6: fused single-pass softmax + aggregation ---------------
__global__ __launch_bounds__(256) void aggregate(const int* __restrict__ off,
                         const int2* __restrict__ sed,
                         const unsigned short* __restrict__ ftb,
                         float* __restrict__ out) {
  int node = (int)((blockIdx.x * blockDim.x + threadIdx.x) >> 6);
  int lane = threadIdx.x & 63;
  if (node >= N_NODES) return;
  int start = off[node], end = off[node + 1];

  f32x4 a0 = (f32x4)0.f, a1 = (f32x4)0.f, a2 = (f32x4)0.f, a3 = (f32x4)0.f;
  float d0 = 0.f, d1 = 0.f, d2 = 0.f, d3 = 0.f;

  int i = start;
  for (; i + 4 <= end; i += 4) {
    int2 e0 = sed[i], e1 = sed[i + 1], e2 = sed[i + 2], e3 = sed[i + 3];
    uint2 v0 = *((const uint2*)(ftb + (size_t)e0.x * OUT_DIM) + lane);
    uint2 v1 = *((const uint2*)(ftb + (size_t)e1.x * OUT_DIM) + lane);
    uint2 v2 = *((const uint2*)(ftb + (size_t)e2.x * OUT_DIM) + lane);
    uint2 v3 = *((const uint2*)(ftb + (size_t)e3.x * OUT_DIM) + lane);
    float w0 = __expf(__int_as_float(e0.y));
    float w1 = __expf(__int_as_float(e1.y));
    float w2 = __expf(__int_as_float(e2.y));
    float w3 = __expf(__int_as_float(e3.y));
    d0 += w0; d1 += w1; d2 += w2; d3 += w3;
    a0[0] += w0 * bf2f((unsigned short)(v0.x & 0xFFFF));
    a0[1] += w0 * bf2f((unsigned short)(v0.x >> 16));
    a0[2] += w0 * bf2f((unsigned short)(v0.y & 0xFFFF));
    a0[3] += w0 * bf2f((unsigned short)(v0.y >> 16));
    a1[0] += w1 * bf2f((unsigned short)(v1.x & 0xFFFF));
    a1[1] += w1 * bf2f((unsigned short)(v1.x >> 16));
    a1[2] += w1 * bf2f((unsigned short)(v1.y & 0xFFFF));
    a1[3] += w1 * bf2f((unsigned short)(v1.y >> 16));
    a2[0] += w2 * bf2f((unsigned short)(v2.x & 0xFFFF));
    a2[1] += w2 * bf2f((unsigned short)(v2.x >> 16));
    a2[2] += w2 * bf2f((unsigned short)(v2.y & 0xFFFF));
    a2[3] += w2 * bf2f((unsigned short)(v2.y >> 16));
    a3[0] += w3 * bf2f((unsigned short)(v3.x & 0xFFFF));
    a3[1] += w3 * bf2f((unsigned short)(v3.x >> 16));
    a3[2] += w3 * bf2f((unsigned short)(v3.y & 0xFFFF));
    a3[3] += w3 * bf2f((unsigned short)(v3.y >> 16));
  }
  for (; i < end; ++i) {
    int2 e0 = sed[i];
    uint2 v0 = *((const uint2*)(ftb + (size_t)e0.x * OUT_DIM) + lane);
    float w0 = __expf(__int_as_float(e0.y));
    d0 += w0;
    a0[0] += w0 * bf2f((unsigned short)(v0.x & 0xFFFF));
    a0[1] += w0 * bf2f((unsigned short)(v0.x >> 16));
    a0[2] += w0 * bf2f((unsigned short)(v0.y & 0xFFFF));
    a0[3] += w0 * bf2f((unsigned short)(v0.y >> 16));
  }

  f32x4 acc = (a0 + a1) + (a2 + a3);
  float dsum = (d0 + d1) + (d2 + d3);
  float inv = (end > start) ? 1.0f / dsum : 0.f;
  acc *= inv;
  __builtin_nontemporal_store(acc, (f32x4*)(out + (size_t)node * OUT_DIM + lane * 4));
}

// ---------------- launch ----------------------------------------------------
extern "C" void kernel_launch(void* const* d_in, const int* in_sizes, int n_in,
                              void* d_out, int out_size, void* d_ws, size_t ws_size,
                              hipStream_t stream) {
  const float* feat = (const float*)d_in[0];
  // d_in[1] = p (unused in eval path)
  const float* Wl = (const float*)d_in[2];
  const float* bl = (const float*)d_in[3];
  const float* Wr = (const float*)d_in[4];
  const float* br = (const float*)d_in[5];
  const float* W  = (const float*)d_in[6];
  const float* b  = (const float*)d_in[7];
  const int* src  = (const int*)d_in[8];
  const int* dst  = (const int*)d_in[9];
  float* out = (float*)d_out;

  char* ws = (char*)d_ws;
  float* el = (float*)ws;            ws += (size_t)N_NODES * 4;
  float* er = (float*)ws;            ws += (size_t)N_NODES * 4;
  unsigned short* Wtp = (unsigned short*)ws;  ws += (size_t)OUT_DIM * IN_DIM * 2;
  unsigned short* ftb = (unsigned short*)ws;  ws += (size_t)N_NODES * OUT_DIM * 2;
  int* deg  = (int*)ws;              ws += (size_t)N_NODES * 4;
  int* cnt  = (int*)ws;              ws += (size_t)N_NODES * 4;
  int* off  = (int*)ws;              ws += (size_t)(N_NODES + 1) * 4;
  int2* sed = (int2*)ws;             ws += (size_t)N_EDGES * 8;
  int* bsum = (int*)ws;              ws += 64 * 4;
  int* bscan = (int*)ws;             ws += 64 * 4;

  hipMemsetAsync(deg, 0, (size_t)N_NODES * 4 * 2, stream);   // deg + cnt

  // allow 32 KB dynamic LDS (host-side, graph-capture-safe, idempotent)
  hipFuncSetAttribute((const void*)gemm_mfma,
                      hipFuncAttributeMaxDynamicSharedMemorySize, 32768);

  wconv<<<(OUT_DIM * IN_DIM) / 256, 256, 0, stream>>>(W, Wtp);
  gemm_mfma<<<(N_NODES + GBM - 1) / GBM, 512, 32768, stream>>>(feat, Wtp, b,
                                                    Wl, bl, Wr, br, ftb, el, er);
  deg_count<<<(N_EDGES + 255) / 256, 256, 0, stream>>>(dst, deg);
  scan_local<<<NBLK_SCAN, 1024, 0, stream>>>(deg, off, bsum);
  scan_bsums<<<1, 64, 0, stream>>>(bsum, bscan, off + N_NODES);
  add_bscan<<<(N_NODES + 255) / 256, 256, 0, stream>>>(off, bscan);
  scatter_edges<<<(N_EDGES + 255) / 256, 256, 0, stream>>>(src, dst, el, er, off, cnt, sed);
  aggregate<<<(N_NODES + 3) / 4, 256, 0, stream>>>(off, sed, ftb, out);
}

// Round 13
// 191.805 us; speedup vs baseline: 1.0215x; 1.0215x over previous
//
#include <hip/hip_runtime.h>
#include <math.h>
#include <stdint.h>

#define N_NODES 50000
#define N_EDGES 800000
#define IN_DIM  512
#define OUT_DIM 256
#define NBLK_SCAN 49   // ceil(50000/1024)

typedef __attribute__((ext_vector_type(8))) short short8;
typedef __attribute__((ext_vector_type(4))) float f32x4;

__device__ inline unsigned f2bf(float x) {
  unsigned u = __float_as_uint(x);
  return (u + 0x7FFFu + ((u >> 16) & 1u)) >> 16;   // RNE
}
__device__ inline float bf2f(unsigned short h) {
  return __uint_as_float(((unsigned)h) << 16);
}

// ---------------- K1: W [512][256] -> Wtp frag-major bf16 -------------------
// Wtp[((nt*16+kk)*64 + lane)*8 + j] = bf16(W[k][c]), k=kk*32+(lane>>4)*8+j,
// c = nt*16 + (lane&15).
__global__ __launch_bounds__(256) void wconv(const float* __restrict__ W,
                                             unsigned short* __restrict__ Wtp) {
  int i = blockIdx.x * 256 + threadIdx.x;   // over 131072
  int c = i & 255, k = i >> 8;              // coalesced read over c
  int nt = c >> 4, kk = k >> 5;
  int lane = (((k & 31) >> 3) << 4) | (c & 15);
  int j = k & 7;
  Wtp[(((size_t)(nt * 16 + kk)) * 64 + lane) * 8 + j] =
      (unsigned short)f2bf(W[(size_t)k * OUT_DIM + c]);
}

// ---------------- K2: ft = bf16(feat @ W + b), feat-in-LDS, W from L2 -------
// block: 512 thr = 8 waves; tile = 32 rows x 256 cols, full K.
// Stage (MLP=8): lane owns row r=wv*4+(lane>>4), chunks c4=(lane&15)+16j,
// j=0..7 -> 8 independent HBM loads; el/er reduced over the 16 lanes of the
// row group (4 shfl steps, all 4 rows in parallel).
// LDS slot swizzle: S(kgrp,row,kk) = (kgrp*16+row) ^ (kk&7) ^ ((row&3)<<1)
// (extra row XOR -> 8 distinct slot%8 -> min-conflict writes).
// byte = ((mg*16+kk)*64 + S)*16 + h*8.
#define GBM 32
__global__ __launch_bounds__(512) void gemm_mfma(const float* __restrict__ feat,
                        const unsigned short* __restrict__ Wtp,
                        const float* __restrict__ bias,
                        const float* __restrict__ Wl, const float* __restrict__ bl,
                        const float* __restrict__ Wr, const float* __restrict__ br,
                        unsigned short* __restrict__ ftb,
                        float* __restrict__ el, float* __restrict__ er) {
  extern __shared__ char smem[];
  const int tid  = threadIdx.x;
  const int lane = tid & 63;
  const int wv   = tid >> 6;          // 0..7
  const int m0   = blockIdx.x * GBM;

  const int l15   = lane & 15;
  const int r     = wv * 4 + (lane >> 4);     // row within tile, 0..31
  const int row16 = r & 15;
  const int mg    = r >> 4;                    // wave-uniform (wv<4 -> 0)
  const int kgrp  = (l15 >> 1) & 3;
  const int b3    = l15 >> 3;                  // kk low bit
  const int h     = lane & 1;                  // 8B half within 16B unit
  int grow = m0 + r;
  int gc   = grow < N_NODES ? grow : N_NODES - 1;
  const float4* frow = (const float4*)(feat + (size_t)gc * IN_DIM);
  const float4* wl4  = (const float4*)Wl;
  const float4* wr4  = (const float4*)Wr;

  float elp = 0.f, erp = 0.f;
  #pragma unroll
  for (int half = 0; half < 2; ++half) {
    // batch of 4 independent loads (j = half*4 .. half*4+3)
    float4 f[4], wlv[4], wrv[4];
    #pragma unroll
    for (int q = 0; q < 4; ++q) {
      int c4 = l15 + 16 * (half * 4 + q);
      f[q]   = frow[c4];
      wlv[q] = wl4[c4];
      wrv[q] = wr4[c4];
    }
    #pragma unroll
    for (int q = 0; q < 4; ++q) {
      int j = half * 4 + q;
      elp += f[q].x * wlv[q].x + f[q].y * wlv[q].y + f[q].z * wlv[q].z + f[q].w * wlv[q].w;
      erp += f[q].x * wrv[q].x + f[q].y * wrv[q].y + f[q].z * wrv[q].z + f[q].w * wrv[q].w;
      uint2 pv;
      pv.x = f2bf(f[q].x) | (f2bf(f[q].y) << 16);
      pv.y = f2bf(f[q].z) | (f2bf(f[q].w) << 16);
      int kk   = 2 * j + b3;
      int slot = (kgrp * 16 + row16) ^ (kk & 7) ^ ((row16 & 3) << 1);
      int boff = (((mg * 16 + kk) * 64) + slot) * 16 + h * 8;
      *(uint2*)(smem + boff) = pv;
    }
  }
  // reduce el/er over the 16 lanes of the row group
  #pragma unroll
  for (int o = 1; o < 16; o <<= 1) {
    elp += __shfl_xor(elp, o);
    erp += __shfl_xor(erp, o);
  }
  if (l15 == 0 && grow < N_NODES) {
    el[grow] = elp + bl[0];
    er[grow] = erp + br[0];
  }
  __syncthreads();

  // ---- compute: LDS feat + L2 W-frags (distance-1 prefetch) + MFMA ----
  f32x4 acc[2][2];
  #pragma unroll
  for (int mgi = 0; mgi < 2; ++mgi) {
    acc[mgi][0] = (f32x4)0.f;
    acc[mgi][1] = (f32x4)0.f;
  }
  const int nt0 = wv * 2;
  const unsigned short* wp0 = Wtp + (((size_t)(nt0 + 0) * 16) * 64 + lane) * 8;
  const unsigned short* wp1 = Wtp + (((size_t)(nt0 + 1) * 16) * 64 + lane) * 8;
  const int rlane = lane & 15;                 // reading row
  short8 w0 = *(const short8*)wp0;
  short8 w1 = *(const short8*)wp1;
  #pragma unroll
  for (int kk = 0; kk < 16; ++kk) {
    short8 nw0, nw1;
    if (kk < 15) {
      nw0 = *(const short8*)(wp0 + (size_t)(kk + 1) * 512);
      nw1 = *(const short8*)(wp1 + (size_t)(kk + 1) * 512);
    }
    int slotr = lane ^ (kk & 7) ^ ((rlane & 3) << 1);
    short8 fa0 = *(const short8*)(smem + (((0 * 16 + kk) * 64) + slotr) * 16);
    short8 fa1 = *(const short8*)(smem + (((1 * 16 + kk) * 64) + slotr) * 16);
    acc[0][0] = __builtin_amdgcn_mfma_f32_16x16x32_bf16(w0, fa0, acc[0][0], 0, 0, 0);
    acc[0][1] = __builtin_amdgcn_mfma_f32_16x16x32_bf16(w1, fa0, acc[0][1], 0, 0, 0);
    acc[1][0] = __builtin_amdgcn_mfma_f32_16x16x32_bf16(w0, fa1, acc[1][0], 0, 0, 0);
    acc[1][1] = __builtin_amdgcn_mfma_f32_16x16x32_bf16(w1, fa1, acc[1][1], 0, 0, 0);
    w0 = nw0; w1 = nw1;
  }

  // ---- store: row = m0+mgi*16+(l&15), col = nt*16 + (l>>4)*4 + reg ----
  #pragma unroll
  for (int mgi = 0; mgi < 2; ++mgi) {
    int row = m0 + mgi * 16 + (lane & 15);
    if (row < N_NODES) {
      unsigned short* orow = ftb + (size_t)row * OUT_DIM;
      #pragma unroll
      for (int t = 0; t < 2; ++t) {
        int col = (nt0 + t) * 16 + (lane >> 4) * 4;
        float4 bb = *(const float4*)(bias + col);
        f32x4 v = acc[mgi][t];
        uint2 pv;
        pv.x = f2bf(v[0] + bb.x) | (f2bf(v[1] + bb.y) << 16);
        pv.y = f2bf(v[2] + bb.z) | (f2bf(v[3] + bb.w) << 16);
        *(uint2*)(orow + col) = pv;
      }
    }
  }
}

// ---------------- K3: degree histogram --------------------------------------
__global__ void deg_count(const int* __restrict__ dst, int* __restrict__ deg) {
  int e = blockIdx.x * blockDim.x + threadIdx.x;
  if (e < N_EDGES) atomicAdd(&deg[dst[e]], 1);
}

// ---------------- K4: parallel exclusive scan (3 stages, shfl-based) --------
__global__ __launch_bounds__(1024) void scan_local(const int* __restrict__ deg,
                                                   int* __restrict__ off,
                                                   int* __restrict__ bsum) {
  __shared__ int wsum[16];
  int b = blockIdx.x, t = threadIdx.x, i = b * 1024 + t;
  int lane = t & 63, wid = t >> 6;
  int v0 = (i < N_NODES) ? deg[i] : 0;
  int v = v0;
  #pragma unroll
  for (int d = 1; d < 64; d <<= 1) {
    int x = __shfl_up(v, d);
    if (lane >= d) v += x;
  }
  if (lane == 63) wsum[wid] = v;
  __syncthreads();
  if (wid == 0) {
    int wv = (lane < 16) ? wsum[lane] : 0;
    int wo = wv;
    #pragma unroll
    for (int d = 1; d < 16; d <<= 1) {
      int x = __shfl_up(wv, d);
      if (lane >= d) wv += x;
    }
    if (lane < 16) wsum[lane] = wv - wo;   // exclusive wave offsets
    if (lane == 15) bsum[b] = wv;          // block total
  }
  __syncthreads();
  if (i < N_NODES) off[i] = (v - v0) + wsum[wid];
}

__global__ void scan_bsums(const int* __restrict__ bsum, int* __restrict__ bscan,
                           int* __restrict__ offN) {
  int t = threadIdx.x;                      // 64 threads, 1 block
  int v = (t < NBLK_SCAN) ? bsum[t] : 0;
  int orig = v;
  for (int d = 1; d < 64; d <<= 1) {
    int x = __shfl_up(v, d);
    if (t >= d) v += x;
  }
  if (t < NBLK_SCAN) bscan[t] = v - orig;   // exclusive
  if (t == NBLK_SCAN - 1) offN[0] = v;      // total == N_EDGES
}

__global__ void add_bscan(int* __restrict__ off, const int* __restrict__ bscan) {
  int i = blockIdx.x * 256 + threadIdx.x;
  if (i < N_NODES) off[i] += bscan[i >> 10];
}

// ---------------- K5: scatter edges into CSR + edge score (int2 packed) -----
__global__ void scatter_edges(const int* __restrict__ src, const int* __restrict__ dst,
                              const float* __restrict__ el, const float* __restrict__ er,
                              const int* __restrict__ off, int* __restrict__ cnt,
                              int2* __restrict__ sed) {
  int e = blockIdx.x * blockDim.x + threadIdx.x;
  if (e >= N_EDGES) return;
  int s = src[e], d = dst[e];
  int pos = off[d] + atomicAdd(&cnt[d], 1);
  float ev = el[s] + er[d];
  ev = (ev > 0.f ? ev : 0.f) + 1.0f;
  int2 pv; pv.x = s; pv.y = __float_as_int(ev);
  sed[pos] = pv;
}

// ---------------- K6: fused single-pass softmax + aggregation ---------------
__global__ __launch_bounds__(256) void aggregate(const int* __restrict__ off,
                         const int2* __restrict__ sed,
                         const unsigned short* __restrict__ ftb,
                         float* __restrict__ out) {
  int node = (int)((blockIdx.x * blockDim.x + threadIdx.x) >> 6);
  int lane = threadIdx.x & 63;
  if (node >= N_NODES) return;
  int start = off[node], end = off[node + 1];

  f32x4 a0 = (f32x4)0.f, a1 = (f32x4)0.f, a2 = (f32x4)0.f, a3 = (f32x4)0.f;
  float d0 = 0.f, d1 = 0.f, d2 = 0.f, d3 = 0.f;

  int i = start;
  for (; i + 4 <= end; i += 4) {
    int2 e0 = sed[i], e1 = sed[i + 1], e2 = sed[i + 2], e3 = sed[i + 3];
    uint2 v0 = *((const uint2*)(ftb + (size_t)e0.x * OUT_DIM) + lane);
    uint2 v1 = *((const uint2*)(ftb + (size_t)e1.x * OUT_DIM) + lane);
    uint2 v2 = *((const uint2*)(ftb + (size_t)e2.x * OUT_DIM) + lane);
    uint2 v3 = *((const uint2*)(ftb + (size_t)e3.x * OUT_DIM) + lane);
    float w0 = __expf(__int_as_float(e0.y));
    float w1 = __expf(__int_as_float(e1.y));
    float w2 = __expf(__int_as_float(e2.y));
    float w3 = __expf(__int_as_float(e3.y));
    d0 += w0; d1 += w1; d2 += w2; d3 += w3;
    a0[0] += w0 * bf2f((unsigned short)(v0.x & 0xFFFF));
    a0[1] += w0 * bf2f((unsigned short)(v0.x >> 16));
    a0[2] += w0 * bf2f((unsigned short)(v0.y & 0xFFFF));
    a0[3] += w0 * bf2f((unsigned short)(v0.y >> 16));
    a1[0] += w1 * bf2f((unsigned short)(v1.x & 0xFFFF));
    a1[1] += w1 * bf2f((unsigned short)(v1.x >> 16));
    a1[2] += w1 * bf2f((unsigned short)(v1.y & 0xFFFF));
    a1[3] += w1 * bf2f((unsigned short)(v1.y >> 16));
    a2[0] += w2 * bf2f((unsigned short)(v2.x & 0xFFFF));
    a2[1] += w2 * bf2f((unsigned short)(v2.x >> 16));
    a2[2] += w2 * bf2f((unsigned short)(v2.y & 0xFFFF));
    a2[3] += w2 * bf2f((unsigned short)(v2.y >> 16));
    a3[0] += w3 * bf2f((unsigned short)(v3.x & 0xFFFF));
    a3[1] += w3 * bf2f((unsigned short)(v3.x >> 16));
    a3[2] += w3 * bf2f((unsigned short)(v3.y & 0xFFFF));
    a3[3] += w3 * bf2f((unsigned short)(v3.y >> 16));
  }
  for (; i < end; ++i) {
    int2 e0 = sed[i];
    uint2 v0 = *((const uint2*)(ftb + (size_t)e0.x * OUT_DIM) + lane);
    float w0 = __expf(__int_as_float(e0.y));
    d0 += w0;
    a0[0] += w0 * bf2f((unsigned short)(v0.x & 0xFFFF));
    a0[1] += w0 * bf2f((unsigned short)(v0.x >> 16));
    a0[2] += w0 * bf2f((unsigned short)(v0.y & 0xFFFF));
    a0[3] += w0 * bf2f((unsigned short)(v0.y >> 16));
  }

  f32x4 acc = (a0 + a1) + (a2 + a3);
  float dsum = (d0 + d1) + (d2 + d3);
  float inv = (end > start) ? 1.0f / dsum : 0.f;
  acc *= inv;
  __builtin_nontemporal_store(acc, (f32x4*)(out + (size_t)node * OUT_DIM + lane * 4));
}

// ---------------- launch ----------------------------------------------------
extern "C" void kernel_launch(void* const* d_in, const int* in_sizes, int n_in,
                              void* d_out, int out_size, void* d_ws, size_t ws_size,
                              hipStream_t stream) {
  const float* feat = (const float*)d_in[0];
  // d_in[1] = p (unused in eval path)
  const float* Wl = (const float*)d_in[2];
  const float* bl = (const float*)d_in[3];
  const float* Wr = (const float*)d_in[4];
  const float* br = (const float*)d_in[5];
  const float* W  = (const float*)d_in[6];
  const float* b  = (const float*)d_in[7];
  const int* src  = (const int*)d_in[8];
  const int* dst  = (const int*)d_in[9];
  float* out = (float*)d_out;

  char* ws = (char*)d_ws;
  float* el = (float*)ws;            ws += (size_t)N_NODES * 4;
  float* er = (float*)ws;            ws += (size_t)N_NODES * 4;
  unsigned short* Wtp = (unsigned short*)ws;  ws += (size_t)OUT_DIM * IN_DIM * 2;
  unsigned short* ftb = (unsigned short*)ws;  ws += (size_t)N_NODES * OUT_DIM * 2;
  int* deg  = (int*)ws;              ws += (size_t)N_NODES * 4;
  int* cnt  = (int*)ws;              ws += (size_t)N_NODES * 4;
  int* off  = (int*)ws;              ws += (size_t)(N_NODES + 1) * 4;
  int2* sed = (int2*)ws;             ws += (size_t)N_EDGES * 8;
  int* bsum = (int*)ws;              ws += 64 * 4;
  int* bscan = (int*)ws;             ws += 64 * 4;

  hipMemsetAsync(deg, 0, (size_t)N_NODES * 4 * 2, stream);   // deg + cnt

  // allow 32 KB dynamic LDS (host-side, graph-capture-safe, idempotent)
  hipFuncSetAttribute((const void*)gemm_mfma,
                      hipFuncAttributeMaxDynamicSharedMemorySize, 32768);

  wconv<<<(OUT_DIM * IN_DIM) / 256, 256, 0, stream>>>(W, Wtp);
  gemm_mfma<<<(N_NODES + GBM - 1) / GBM, 512, 32768, stream>>>(feat, Wtp, b,
                                                    Wl, bl, Wr, br, ftb, el, er);
  deg_count<<<(N_EDGES + 255) / 256, 256, 0, stream>>>(dst, deg);
  scan_local<<<NBLK_SCAN, 1024, 0, stream>>>(deg, off, bsum);
  scan_bsums<<<1, 64, 0, stream>>>(bsum, bscan, off + N_NODES);
  add_bscan<<<(N_NODES + 255) / 256, 256, 0, stream>>>(off, bscan);
  scatter_edges<<<(N_EDGES + 255) / 256, 256, 0, stream>>>(src, dst, el, er, off, cnt, sed);
  aggregate<<<(N_NODES + 3) / 4, 256, 0, stream>>>(off, sed, ftb, out);
}